// Round 3
// baseline (209.580 us; speedup 1.0000x reference)
//
#include <hip/hip_runtime.h>
#include <stdint.h>

#define M_PIX 8192
#define N_CB  16384
#define KD    256

typedef float f32x4 __attribute__((ext_vector_type(4)));
typedef int   i32x4 __attribute__((ext_vector_type(4)));
typedef int   i32x8 __attribute__((ext_vector_type(8)));
typedef unsigned long long ull;

// workspace layout (bytes)
#define OFF_CF8  (0ULL)            // codebook fp8 e4m3 (linear rows) : 4 MB
#define OFF_XF8  (4ULL << 20)      // x fp8 e4m3 (linear rows)        : 2 MB
#define OFF_CBSQ (6ULL << 20)      // ||c||^2 fp32                    : 64 KB
#define OFF_SLOT (7ULL << 20)      // float2 top2 [tile][pixel]       : 8 MB
#define WS_REQ   (15ULL << 20)

__device__ __forceinline__ unsigned int fkey(float s) {
  unsigned int f = __float_as_uint(s);
  return f ^ ((unsigned int)(((int)f) >> 31) | 0x80000000u);
}
// fp32 -> OCP e4m3fn, RNE, handles subnormals (step 2^-9), clamp 448
__device__ __forceinline__ unsigned char f2e4m3(float v) {
  float av = fminf(fabsf(v), 448.0f);
  const unsigned s = (__float_as_uint(v) >> 24) & 0x80u;
  unsigned m;
  if (av >= 0.015625f) {              // normal: round at mantissa bit 20
    unsigned u = __float_as_uint(av);
    u += 0x7FFFFu + ((u >> 20) & 1u);
    m = (((u >> 23) - 120u) << 3) | ((u >> 20) & 7u);
  } else {                            // subnormal
    m = (unsigned)(int)rintf(av * 512.0f);
  }
  return (unsigned char)(s | m);
}
// keep-smallest-2 on packed float keys: 3 VALU, no cndmask
__device__ __forceinline__ void ins2f(float k, float& v1, float& v2) {
  v2 = fminf(v2, fmaxf(v1, k));   // uses OLD v1
  v1 = fminf(v1, k);
}
// 32B fragment load straight from global (two dwordx4); 32B-aligned
__device__ __forceinline__ i32x8 gload32(const unsigned char* p) {
  const i32x4 lo = *(const i32x4*)(const void*)p;
  const i32x4 hi = *(const i32x4*)(const void*)(p + 16);
  return (i32x8){lo.x, lo.y, lo.z, lo.w, hi.x, hi.y, hi.z, hi.w};
}

// ---------------- kernel 1: fp32 -> fp8 e4m3 linear rows + cb norms ---------
__global__ __launch_bounds__(256) void prep_kernel(
    const float* __restrict__ x, const float* __restrict__ cb,
    unsigned char* __restrict__ Cf8, unsigned char* __restrict__ Xf8,
    float* __restrict__ cbsq) {
  const int wid = threadIdx.x >> 6, lane = threadIdx.x & 63;
  const int row = blockIdx.x * 4 + wid;        // grid = (N_CB+M_PIX)/4
  const bool isCb = (row < N_CB);
  const int rowL = isCb ? row : row - N_CB;
  const float* src = (isCb ? cb : x) + (size_t)rowL * KD;
  const float4 v = ((const float4*)src)[lane];
  uchar4 pk;
  pk.x = f2e4m3(v.x); pk.y = f2e4m3(v.y); pk.z = f2e4m3(v.z); pk.w = f2e4m3(v.w);
  *(uchar4*)(void*)((isCb ? Cf8 : Xf8) + (size_t)rowL * KD + lane * 4) = pk;
  if (isCb) {
    float ss = v.x*v.x + v.y*v.y + v.z*v.z + v.w*v.w;   // fp32 norm
    #pragma unroll
    for (int off = 32; off > 0; off >>= 1) ss += __shfl_xor(ss, off);
    if (lane == 0) cbsq[rowL] = ss;
  }
}

// ---------------- kernel 2: MX-fp8 GEMM (identity scales) + per-tile top-2 --
// s[p,n] = cbsq[n] - 2*(x8.c8). 8192 blocks / 4 waves (2x2, wave tile 64x64).
// NEW (this round): REGISTER-DIRECT GEMM. The 16x16x128 fragment is 32
// contiguous bytes/lane at row*256 + q*32 — a wave's frag load is 16 full
// 128B lines, perfectly coalesced. A (2 MB) and the per-XCD B strip (512 KB)
// are L2-resident under the XCD swizzle, so fragments are loaded straight
// from global into VGPRs: no LDS staging, no global_load_lds, no swizzle,
// no mid-GEMM barriers, no frag ds_reads (and no LDS bank conflicts).
// Waves are fully independent until the epilogue; latency hiding is pure TLP.
// LDS holds only the epilogue overlay planes [128][36] fp32 (36864 B ->
// 4 blocks/CU by LDS; VGPR ~150 -> 3 waves/SIMD is the binding cap).
// MFMA inputs are byte-identical to the LDS version -> output unchanged.

__global__ __launch_bounds__(256, 3) void gemm_top2_kernel(
    const unsigned char* __restrict__ Xf8, const unsigned char* __restrict__ Cf8,
    const float* __restrict__ cbsq, float2* __restrict__ slots) {
  __shared__ __align__(16) float smem[9216];   // 36864 B
  float* v1p = smem;                           // [128][36]
  float* v2p = smem + 4608;                    // [128][36]

  const int tid = threadIdx.x;
  const int wid = tid >> 6, lane = tid & 63;
  const int wy = wid >> 1, wx = wid & 1;
  const int q = lane >> 4, c = lane & 15;

  // m-outer / n-inner per XCD: 16-block sweeps share one A-tile + B-strip
  const int bx = blockIdx.x & 7, bg = blockIdx.x >> 3;
  const int mt = bg >> 4;               // 0..63
  const int nt = bx * 16 + (bg & 15);   // 0..127
  const int m0 = mt * 128, n0 = nt * 128;

  // per-lane fragment base addresses (lane holds row=c(+16*i), k=q*32..+32)
  const unsigned char* Abase = Xf8 + (size_t)(m0 + wy * 64 + c) * KD + q * 32;
  const unsigned char* Bbase = Cf8 + (size_t)(n0 + wx * 64 + c) * KD + q * 32;

  const f32x4 zf = {0.f, 0.f, 0.f, 0.f};
  f32x4 acc[4][4];
  #pragma unroll
  for (int i = 0; i < 4; i++)
    #pragma unroll
    for (int j = 0; j < 4; j++) acc[i][j] = zf;

  #pragma unroll
  for (int hk = 0; hk < 2; hk++) {      // two 128-col K-halves
    const int ho = hk * 128;
    i32x8 bf[4], af[4];
    #pragma unroll
    for (int ni = 0; ni < 4; ni++) bf[ni] = gload32(Bbase + ni * 16 * KD + ho);
    #pragma unroll
    for (int mi = 0; mi < 4; mi++) af[mi] = gload32(Abase + mi * 16 * KD + ho);
    #pragma unroll
    for (int mi = 0; mi < 4; mi++)
      #pragma unroll
      for (int ni = 0; ni < 4; ni++)
        acc[mi][ni] = __builtin_amdgcn_mfma_scale_f32_16x16x128_f8f6f4(
            af[mi], bf[ni], acc[mi][ni], 0, 0,
            0, 0x7F7F7F7F,    // A scales: E8M0 127 = 1.0
            0, 0x7F7F7F7F);   // B scales: identity
  }

  float cs[4]; unsigned colp[4];
  #pragma unroll
  for (int ni = 0; ni < 4; ni++) {
    colp[ni] = wx * 64 + ni * 16 + c;
    cs[ni] = cbsq[n0 + colp[ni]];
  }

  // owner phase: C/D layout col=lane&15, row=q*4+reg (m89/m91); col packed
  // into low 7 mantissa bits (|err|<=0.008, absorbed by k3 threshold).
  // top-2-of-4 via 8-op sorting network (vs 12-op ins2f chain).
  #pragma unroll
  for (int mi = 0; mi < 4; mi++) {
    #pragma unroll
    for (int r = 0; r < 4; r++) {
      float k[4];
      #pragma unroll
      for (int ni = 0; ni < 4; ni++) {
        const float s = fmaf(-2.f, acc[mi][ni][r], cs[ni]);
        k[ni] = __uint_as_float((__float_as_uint(s) & 0xFFFFFF80u) | colp[ni]);
      }
      const float m1 = fminf(k[0], k[1]), M1 = fmaxf(k[0], k[1]);
      const float m2 = fminf(k[2], k[3]), M2 = fmaxf(k[2], k[3]);
      const float v1 = fminf(m1, m2);
      const float v2 = fminf(fmaxf(m1, m2), fminf(M1, M2));
      const int row = wy * 64 + mi * 16 + q * 4 + r;
      const int slot = wx * 16 + c;
      v1p[row * 36 + slot] = v1;
      v2p[row * 36 + slot] = v2;
    }
  }
  __syncthreads();

  // scan: 2 threads/row over 16 partial-pairs each, 1 shuffle merge
  {
    const float FINF = __uint_as_float(0x7F800000u);
    const int srow = tid >> 1, half = tid & 1;
    float v1 = FINF, v2 = FINF;
    #pragma unroll
    for (int jj = 0; jj < 2; jj++) {
      const float4 a = *(const float4*)(const void*)(v1p + srow * 36 + half * 16 + jj * 8);
      const float4 a2 = *(const float4*)(const void*)(v1p + srow * 36 + half * 16 + jj * 8 + 4);
      const float4 b = *(const float4*)(const void*)(v2p + srow * 36 + half * 16 + jj * 8);
      const float4 b2 = *(const float4*)(const void*)(v2p + srow * 36 + half * 16 + jj * 8 + 4);
      ins2f(a.x, v1, v2);  ins2f(a.y, v1, v2);
      ins2f(a.z, v1, v2);  ins2f(a.w, v1, v2);
      ins2f(a2.x, v1, v2); ins2f(a2.y, v1, v2);
      ins2f(a2.z, v1, v2); ins2f(a2.w, v1, v2);
      ins2f(b.x, v1, v2);  ins2f(b.y, v1, v2);
      ins2f(b.z, v1, v2);  ins2f(b.w, v1, v2);
      ins2f(b2.x, v1, v2); ins2f(b2.y, v1, v2);
      ins2f(b2.z, v1, v2); ins2f(b2.w, v1, v2);
    }
    const float b1 = __shfl_xor(v1, 1), b2 = __shfl_xor(v2, 1);
    const float hi = fmaxf(v1, b1);
    v1 = fminf(v1, b1);
    v2 = fminf(fminf(v2, b2), hi);
    if (!half)
      slots[(size_t)nt * M_PIX + m0 + srow] = make_float2(v1, v2);
  }
}

// ---------------- kernel 3: global min + threshold exact rescore + gather ---
// Candidates with observed score < min+10 (noise + pack err + margin) are
// rescored exactly in fp32 (reads ORIGINAL fp32 cb rows); avg ~2 per pixel.
__global__ __launch_bounds__(256) void reduce_rescore_gather(
    const float* __restrict__ x, const float* __restrict__ cb,
    const float* __restrict__ cbsq, const float2* __restrict__ slots,
    float* __restrict__ out) {
  const int wid = threadIdx.x >> 6, lane = threadIdx.x & 63;
  const int pixel = blockIdx.x * 4 + wid;     // grid = 8192/4

  const float2 sA = slots[(size_t)lane * M_PIX + pixel];
  const float2 sB = slots[(size_t)(64 + lane) * M_PIX + pixel];
  const float sc[4] = {sA.x, sA.y, sB.x, sB.y};
  float mn = fminf(fminf(sc[0], sc[1]), fminf(sc[2], sc[3]));
  #pragma unroll
  for (int off = 1; off < 64; off <<= 1) mn = fminf(mn, __shfl_xor(mn, off));
  const float thr = mn + 10.0f;

  const float4 xv = ((const float4*)x)[(size_t)pixel * 64 + lane];
  ull best = ~0ULL;
  #pragma unroll
  for (int j = 0; j < 4; j++) {
    ull mask = __ballot(sc[j] < thr);
    while (mask) {
      const int src = (int)__ffsll((long long)mask) - 1;
      mask &= mask - 1;
      const float val = __shfl(sc[j], src);
      const unsigned ij = (unsigned)(((j >> 1) * 64 + src) * 128) +
                          (__float_as_uint(val) & 127u);
      const float4 cv = ((const float4*)cb)[(size_t)ij * 64 + lane];
      float d = xv.x*cv.x + xv.y*cv.y + xv.z*cv.z + xv.w*cv.w;
      #pragma unroll
      for (int off = 1; off < 64; off <<= 1) d += __shfl_xor(d, off);
      const float sv = fmaf(-2.f, d, cbsq[ij]);
      const ull k = ((ull)fkey(sv) << 32) | ij;   // tie -> lowest idx (np)
      best = k < best ? k : best;
    }
  }
  const unsigned w = (unsigned)best;
  ((float4*)out)[(size_t)pixel * 64 + lane] = ((const float4*)cb)[(size_t)w * 64 + lane];
}

// ---------------- fallback (ws too small): exact fp32 scan ------------------
__global__ __launch_bounds__(256) void fallback_kernel(
    const float* __restrict__ x, const float* __restrict__ cb,
    float* __restrict__ out) {
  __shared__ float xs[256];
  __shared__ unsigned long long keys[4];
  __shared__ int widx;
  const int p = blockIdx.x;
  const int tid = threadIdx.x, wid = tid >> 6, lane = tid & 63;
  xs[tid] = x[(size_t)p * KD + tid];
  __syncthreads();
  const float4 xv = ((const float4*)xs)[lane];
  float bestS = 3.4e38f; int bestI = 0;
  for (int k = wid; k < N_CB; k += 4) {
    const float4 cv = ((const float4*)cb)[(size_t)k * 64 + lane];
    float t = cv.x*(cv.x - 2.f*xv.x) + cv.y*(cv.y - 2.f*xv.y)
            + cv.z*(cv.z - 2.f*xv.z) + cv.w*(cv.w - 2.f*xv.w);
    #pragma unroll
    for (int off = 1; off < 64; off <<= 1) t += __shfl_xor(t, off);
    if (t < bestS) { bestS = t; bestI = k; }
  }
  if (lane == 0)
    keys[wid] = ((unsigned long long)fkey(bestS) << 32) | (unsigned int)bestI;
  __syncthreads();
  if (tid == 0) {
    unsigned long long m = keys[0];
    for (int i = 1; i < 4; i++) if (keys[i] < m) m = keys[i];
    widx = (int)(unsigned int)(m & 0xFFFFFFFFULL);
  }
  __syncthreads();
  out[(size_t)p * KD + tid] = cb[(size_t)widx * KD + tid];
}

extern "C" void kernel_launch(void* const* d_in, const int* in_sizes, int n_in,
                              void* d_out, int out_size, void* d_ws, size_t ws_size,
                              hipStream_t stream) {
  const float* x  = (const float*)d_in[0];   // [8192,256]
  const float* cb = (const float*)d_in[1];   // [16384,256]
  float* out = (float*)d_out;                // [8192,256]

  if (ws_size < WS_REQ) {
    fallback_kernel<<<M_PIX, 256, 0, stream>>>(x, cb, out);
    return;
  }

  char* ws = (char*)d_ws;
  unsigned char* Cf8 = (unsigned char*)(ws + OFF_CF8);
  unsigned char* Xf8 = (unsigned char*)(ws + OFF_XF8);
  float* cbsq        = (float*)(ws + OFF_CBSQ);
  float2* slots      = (float2*)(ws + OFF_SLOT);

  prep_kernel<<<(N_CB + M_PIX) / 4, 256, 0, stream>>>(x, cb, Cf8, Xf8, cbsq);
  gemm_top2_kernel<<<M_PIX, 256, 0, stream>>>(Xf8, Cf8, cbsq, slots);
  reduce_rescore_gather<<<M_PIX / 4, 256, 0, stream>>>(x, cb, cbsq, slots, out);
}

// Round 4
// 168.881 us; speedup vs baseline: 1.2410x; 1.2410x over previous
//
#include <hip/hip_runtime.h>
#include <stdint.h>

#define M_PIX 8192
#define N_CB  16384
#define KD    256

typedef float f32x4 __attribute__((ext_vector_type(4)));
typedef int   i32x4 __attribute__((ext_vector_type(4)));
typedef int   i32x8 __attribute__((ext_vector_type(8)));
typedef unsigned long long ull;

// workspace layout (bytes)
#define OFF_CF8  (0ULL)            // codebook fp8 e4m3 (linear rows) : 4 MB
#define OFF_XF8  (4ULL << 20)      // x fp8 e4m3 (linear rows)        : 2 MB
#define OFF_CBSQ (6ULL << 20)      // ||c||^2 fp32                    : 64 KB
#define OFF_SLOT (7ULL << 20)      // float2 top2 [tile][pixel]       : 8 MB
#define WS_REQ   (15ULL << 20)

__device__ __forceinline__ unsigned int fkey(float s) {
  unsigned int f = __float_as_uint(s);
  return f ^ ((unsigned int)(((int)f) >> 31) | 0x80000000u);
}
// fp32 -> OCP e4m3fn, RNE, handles subnormals (step 2^-9), clamp 448
__device__ __forceinline__ unsigned char f2e4m3(float v) {
  float av = fminf(fabsf(v), 448.0f);
  const unsigned s = (__float_as_uint(v) >> 24) & 0x80u;
  unsigned m;
  if (av >= 0.015625f) {              // normal: round at mantissa bit 20
    unsigned u = __float_as_uint(av);
    u += 0x7FFFFu + ((u >> 20) & 1u);
    m = (((u >> 23) - 120u) << 3) | ((u >> 20) & 7u);
  } else {                            // subnormal
    m = (unsigned)(int)rintf(av * 512.0f);
  }
  return (unsigned char)(s | m);
}
__device__ __forceinline__ void gl_lds16(const unsigned char* g, char* l) {
  __builtin_amdgcn_global_load_lds(
      (const __attribute__((address_space(1))) unsigned int*)(const void*)g,
      (__attribute__((address_space(3))) unsigned int*)(void*)l,
      16, 0, 0);
}
// keep-smallest-2 on packed float keys: 3 VALU, no cndmask
__device__ __forceinline__ void ins2f(float k, float& v1, float& v2) {
  v2 = fminf(v2, fmaxf(v1, k));   // uses OLD v1
  v1 = fminf(v1, k);
}
// 32B fragment load straight from global (two dwordx4); 32B-aligned
__device__ __forceinline__ i32x8 gload32(const unsigned char* p) {
  const i32x4 lo = *(const i32x4*)(const void*)p;
  const i32x4 hi = *(const i32x4*)(const void*)(p + 16);
  return (i32x8){lo.x, lo.y, lo.z, lo.w, hi.x, hi.y, hi.z, hi.w};
}
// 32B fragment read from swizzled LDS: addr and addr^16
__device__ __forceinline__ i32x8 ld32(const char* p, int addr) {
  const i32x4 lo = *(const i32x4*)(const void*)(p + addr);
  const i32x4 hi = *(const i32x4*)(const void*)(p + (addr ^ 16));
  return (i32x8){lo.x, lo.y, lo.z, lo.w, hi.x, hi.y, hi.z, hi.w};
}

// ---------------- kernel 1: fp32 -> fp8 e4m3 linear rows + cb norms ---------
__global__ __launch_bounds__(256) void prep_kernel(
    const float* __restrict__ x, const float* __restrict__ cb,
    unsigned char* __restrict__ Cf8, unsigned char* __restrict__ Xf8,
    float* __restrict__ cbsq) {
  const int wid = threadIdx.x >> 6, lane = threadIdx.x & 63;
  const int row = blockIdx.x * 4 + wid;        // grid = (N_CB+M_PIX)/4
  const bool isCb = (row < N_CB);
  const int rowL = isCb ? row : row - N_CB;
  const float* src = (isCb ? cb : x) + (size_t)rowL * KD;
  const float4 v = ((const float4*)src)[lane];
  uchar4 pk;
  pk.x = f2e4m3(v.x); pk.y = f2e4m3(v.y); pk.z = f2e4m3(v.z); pk.w = f2e4m3(v.w);
  *(uchar4*)(void*)((isCb ? Cf8 : Xf8) + (size_t)rowL * KD + lane * 4) = pk;
  if (isCb) {
    float ss = v.x*v.x + v.y*v.y + v.z*v.z + v.w*v.w;   // fp32 norm
    #pragma unroll
    for (int off = 32; off > 0; off >>= 1) ss += __shfl_xor(ss, off);
    if (lane == 0) cbsq[rowL] = ss;
  }
}

// ---------------- kernel 2: MX-fp8 GEMM (identity scales) + per-tile top-2 --
// s[p,n] = cbsq[n] - 2*(x8.c8). 8192 blocks / 4 waves (2x2, wave tile 64x64).
// HYBRID pipe-split (this round):
//  - A (x rows) staged in LDS exactly as in R1: two 16 KB half-planes,
//    row stride 128 B, XOR-swizzled via pre-swizzled global source of
//    global_load_lds; frag read = 2 x ds_read_b128 (2-way = free).
//  - B (codebook rows) loaded DIRECT global->VGPR: all 16 frag loads
//    (both K-halves, 64 VGPR) issued at the very top, ~2000 cy before
//    first use -> L2 latency hidden under A-staging (fixes R3's stall,
//    where loads were issued just-in-time). B strip (512 KB/XCD) is
//    L2-resident under the XCD swizzle.
// This halves the per-block LDS-pipe load (R1's limiter: every staged byte
// was read twice through the 128 B/cy LDS pipe); B traffic moves to the
// separate vector-memory (L2) pipe.
// Wait structure: issue B0,B1 gloads -> A0,A1 global_load_lds ->
// vmcnt(4) [B0,B1,A0 landed; A1 in flight] + barrier -> compute h0 ->
// vmcnt(0) + barrier -> compute h1. MFMA inputs/order byte-identical to R1.
// Epilogue planes [128][36] fp32 overlay the A planes after __syncthreads.

__global__ __launch_bounds__(256, 2) void gemm_top2_kernel(
    const unsigned char* __restrict__ Xf8, const unsigned char* __restrict__ Cf8,
    const float* __restrict__ cbsq, float2* __restrict__ slots) {
  __shared__ __align__(16) float smem[9216];   // 36864 B
  char* A_s = (char*)smem;                     // A0 @0, A1 @16384 (32 KB)
  float* v1p = smem;                           // overlay: [128][36]
  float* v2p = smem + 4608;                    // overlay: [128][36]

  const int tid = threadIdx.x;
  const int wid = tid >> 6, lane = tid & 63;
  const int wy = wid >> 1, wx = wid & 1;
  const int q = lane >> 4, c = lane & 15;

  // m-outer / n-inner per XCD: 16-block sweeps share one A-tile + B-strip
  const int bx = blockIdx.x & 7, bg = blockIdx.x >> 3;
  const int mt = bg >> 4;               // 0..63
  const int nt = bx * 16 + (bg & 15);   // 0..127
  const int m0 = mt * 128, n0 = nt * 128;

  // ---- B fragments: direct global loads, both halves, issued first ----
  const unsigned char* Bbase = Cf8 + (size_t)(n0 + wx * 64 + c) * KD + q * 32;
  i32x8 bf0[4], bf1[4];
  #pragma unroll
  for (int ni = 0; ni < 4; ni++) bf0[ni] = gload32(Bbase + ni * 16 * KD);
  #pragma unroll
  for (int ni = 0; ni < 4; ni++) bf1[ni] = gload32(Bbase + ni * 16 * KD + 128);
  __builtin_amdgcn_sched_barrier(0);    // pin: B loads issue before A staging

  // ---- A staging: inverse-swizzled global source, linear LDS dest ----
  const int srow8 = lane >> 3;                       // row within 8-row chunk
  const int sgb = ((lane & 7) ^ srow8) * 16;         // pre-swizzled 16B slot
  #pragma unroll
  for (int hk = 0; hk < 2; hk++) {
    #pragma unroll
    for (int j = 0; j < 4; j++) {       // 16 chunks of 1 KB per half
      const int chunk = j * 4 + wid;    // wave-uniform
      const int row = chunk * 8 + srow8;
      gl_lds16(Xf8 + (size_t)(m0 + row) * KD + sgb + hk * 128,
               A_s + hk * 16384 + chunk * 1024);
    }
    __builtin_amdgcn_sched_barrier(0);  // pin A0-before-A1 issue order
  }

  // per-lane swizzled A frag byte addresses (within a 16 KB half-plane)
  const int swz = (c & 7) << 4;
  int aaddr[4];
  #pragma unroll
  for (int i = 0; i < 4; i++)
    aaddr[i] = ((((wy * 64 + i * 16 + c) * 128) + q * 32) ^ swz);

  const f32x4 zf = {0.f, 0.f, 0.f, 0.f};
  f32x4 acc[4][4];
  #pragma unroll
  for (int i = 0; i < 4; i++)
    #pragma unroll
    for (int j = 0; j < 4; j++) acc[i][j] = zf;

  asm volatile("s_waitcnt vmcnt(4)" ::: "memory");   // B0,B1,A0 landed
  __builtin_amdgcn_s_barrier();                      // all waves' A0 landed
  __builtin_amdgcn_sched_barrier(0);

  #pragma unroll
  for (int mi = 0; mi < 4; mi++) {      // ---- compute half 0 ----
    const i32x8 af = ld32(A_s, aaddr[mi]);
    #pragma unroll
    for (int ni = 0; ni < 4; ni++)
      acc[mi][ni] = __builtin_amdgcn_mfma_scale_f32_16x16x128_f8f6f4(
          af, bf0[ni], acc[mi][ni], 0, 0,
          0, 0x7F7F7F7F, 0, 0x7F7F7F7F);
  }

  __builtin_amdgcn_sched_barrier(0);
  asm volatile("s_waitcnt vmcnt(0)" ::: "memory");   // own A1 landed
  __builtin_amdgcn_s_barrier();                      // all waves' A1 landed
  __builtin_amdgcn_sched_barrier(0);

  #pragma unroll
  for (int mi = 0; mi < 4; mi++) {      // ---- compute half 1 ----
    const i32x8 af = ld32(A_s, aaddr[mi] + 16384);
    #pragma unroll
    for (int ni = 0; ni < 4; ni++)
      acc[mi][ni] = __builtin_amdgcn_mfma_scale_f32_16x16x128_f8f6f4(
          af, bf1[ni], acc[mi][ni], 0, 0,
          0, 0x7F7F7F7F, 0, 0x7F7F7F7F);
  }

  __syncthreads();   // frag reads drained; A planes dead -> overlay planes

  float cs[4]; unsigned colp[4];
  #pragma unroll
  for (int ni = 0; ni < 4; ni++) {
    colp[ni] = wx * 64 + ni * 16 + c;
    cs[ni] = cbsq[n0 + colp[ni]];
  }

  // owner phase: C/D layout col=lane&15, row=q*4+reg (m89/m91); col packed
  // into low 7 mantissa bits (|err|<=0.008, absorbed by k3 threshold).
  // top-2-of-4 via 8-op sorting network.
  #pragma unroll
  for (int mi = 0; mi < 4; mi++) {
    #pragma unroll
    for (int r = 0; r < 4; r++) {
      float k[4];
      #pragma unroll
      for (int ni = 0; ni < 4; ni++) {
        const float s = fmaf(-2.f, acc[mi][ni][r], cs[ni]);
        k[ni] = __uint_as_float((__float_as_uint(s) & 0xFFFFFF80u) | colp[ni]);
      }
      const float m1 = fminf(k[0], k[1]), M1 = fmaxf(k[0], k[1]);
      const float m2 = fminf(k[2], k[3]), M2 = fmaxf(k[2], k[3]);
      const float v1 = fminf(m1, m2);
      const float v2 = fminf(fmaxf(m1, m2), fminf(M1, M2));
      const int row = wy * 64 + mi * 16 + q * 4 + r;
      const int slot = wx * 16 + c;
      v1p[row * 36 + slot] = v1;
      v2p[row * 36 + slot] = v2;
    }
  }
  __syncthreads();

  // scan: 2 threads/row over 16 partial-pairs each, 1 shuffle merge
  {
    const float FINF = __uint_as_float(0x7F800000u);
    const int srow = tid >> 1, half = tid & 1;
    float v1 = FINF, v2 = FINF;
    #pragma unroll
    for (int jj = 0; jj < 2; jj++) {
      const float4 a = *(const float4*)(const void*)(v1p + srow * 36 + half * 16 + jj * 8);
      const float4 a2 = *(const float4*)(const void*)(v1p + srow * 36 + half * 16 + jj * 8 + 4);
      const float4 b = *(const float4*)(const void*)(v2p + srow * 36 + half * 16 + jj * 8);
      const float4 b2 = *(const float4*)(const void*)(v2p + srow * 36 + half * 16 + jj * 8 + 4);
      ins2f(a.x, v1, v2);  ins2f(a.y, v1, v2);
      ins2f(a.z, v1, v2);  ins2f(a.w, v1, v2);
      ins2f(a2.x, v1, v2); ins2f(a2.y, v1, v2);
      ins2f(a2.z, v1, v2); ins2f(a2.w, v1, v2);
      ins2f(b.x, v1, v2);  ins2f(b.y, v1, v2);
      ins2f(b.z, v1, v2);  ins2f(b.w, v1, v2);
      ins2f(b2.x, v1, v2); ins2f(b2.y, v1, v2);
      ins2f(b2.z, v1, v2); ins2f(b2.w, v1, v2);
    }
    const float b1 = __shfl_xor(v1, 1), b2 = __shfl_xor(v2, 1);
    const float hi = fmaxf(v1, b1);
    v1 = fminf(v1, b1);
    v2 = fminf(fminf(v2, b2), hi);
    if (!half)
      slots[(size_t)nt * M_PIX + m0 + srow] = make_float2(v1, v2);
  }
}

// ---------------- kernel 3: global min + threshold exact rescore + gather ---
// Candidates with observed score < min+10 (noise + pack err + margin) are
// rescored exactly in fp32 (reads ORIGINAL fp32 cb rows); avg ~2 per pixel.
__global__ __launch_bounds__(256) void reduce_rescore_gather(
    const float* __restrict__ x, const float* __restrict__ cb,
    const float* __restrict__ cbsq, const float2* __restrict__ slots,
    float* __restrict__ out) {
  const int wid = threadIdx.x >> 6, lane = threadIdx.x & 63;
  const int pixel = blockIdx.x * 4 + wid;     // grid = 8192/4

  const float2 sA = slots[(size_t)lane * M_PIX + pixel];
  const float2 sB = slots[(size_t)(64 + lane) * M_PIX + pixel];
  const float sc[4] = {sA.x, sA.y, sB.x, sB.y};
  float mn = fminf(fminf(sc[0], sc[1]), fminf(sc[2], sc[3]));
  #pragma unroll
  for (int off = 1; off < 64; off <<= 1) mn = fminf(mn, __shfl_xor(mn, off));
  const float thr = mn + 10.0f;

  const float4 xv = ((const float4*)x)[(size_t)pixel * 64 + lane];
  ull best = ~0ULL;
  #pragma unroll
  for (int j = 0; j < 4; j++) {
    ull mask = __ballot(sc[j] < thr);
    while (mask) {
      const int src = (int)__ffsll((long long)mask) - 1;
      mask &= mask - 1;
      const float val = __shfl(sc[j], src);
      const unsigned ij = (unsigned)(((j >> 1) * 64 + src) * 128) +
                          (__float_as_uint(val) & 127u);
      const float4 cv = ((const float4*)cb)[(size_t)ij * 64 + lane];
      float d = xv.x*cv.x + xv.y*cv.y + xv.z*cv.z + xv.w*cv.w;
      #pragma unroll
      for (int off = 1; off < 64; off <<= 1) d += __shfl_xor(d, off);
      const float sv = fmaf(-2.f, d, cbsq[ij]);
      const ull k = ((ull)fkey(sv) << 32) | ij;   // tie -> lowest idx (np)
      best = k < best ? k : best;
    }
  }
  const unsigned w = (unsigned)best;
  ((float4*)out)[(size_t)pixel * 64 + lane] = ((const float4*)cb)[(size_t)w * 64 + lane];
}

// ---------------- fallback (ws too small): exact fp32 scan ------------------
__global__ __launch_bounds__(256) void fallback_kernel(
    const float* __restrict__ x, const float* __restrict__ cb,
    float* __restrict__ out) {
  __shared__ float xs[256];
  __shared__ unsigned long long keys[4];
  __shared__ int widx;
  const int p = blockIdx.x;
  const int tid = threadIdx.x, wid = tid >> 6, lane = tid & 63;
  xs[tid] = x[(size_t)p * KD + tid];
  __syncthreads();
  const float4 xv = ((const float4*)xs)[lane];
  float bestS = 3.4e38f; int bestI = 0;
  for (int k = wid; k < N_CB; k += 4) {
    const float4 cv = ((const float4*)cb)[(size_t)k * 64 + lane];
    float t = cv.x*(cv.x - 2.f*xv.x) + cv.y*(cv.y - 2.f*xv.y)
            + cv.z*(cv.z - 2.f*xv.z) + cv.w*(cv.w - 2.f*xv.w);
    #pragma unroll
    for (int off = 1; off < 64; off <<= 1) t += __shfl_xor(t, off);
    if (t < bestS) { bestS = t; bestI = k; }
  }
  if (lane == 0)
    keys[wid] = ((unsigned long long)fkey(bestS) << 32) | (unsigned int)bestI;
  __syncthreads();
  if (tid == 0) {
    unsigned long long m = keys[0];
    for (int i = 1; i < 4; i++) if (keys[i] < m) m = keys[i];
    widx = (int)(unsigned int)(m & 0xFFFFFFFFULL);
  }
  __syncthreads();
  out[(size_t)p * KD + tid] = cb[(size_t)widx * KD + tid];
}

extern "C" void kernel_launch(void* const* d_in, const int* in_sizes, int n_in,
                              void* d_out, int out_size, void* d_ws, size_t ws_size,
                              hipStream_t stream) {
  const float* x  = (const float*)d_in[0];   // [8192,256]
  const float* cb = (const float*)d_in[1];   // [16384,256]
  float* out = (float*)d_out;                // [8192,256]

  if (ws_size < WS_REQ) {
    fallback_kernel<<<M_PIX, 256, 0, stream>>>(x, cb, out);
    return;
  }

  char* ws = (char*)d_ws;
  unsigned char* Cf8 = (unsigned char*)(ws + OFF_CF8);
  unsigned char* Xf8 = (unsigned char*)(ws + OFF_XF8);
  float* cbsq        = (float*)(ws + OFF_CBSQ);
  float2* slots      = (float2*)(ws + OFF_SLOT);

  prep_kernel<<<(N_CB + M_PIX) / 4, 256, 0, stream>>>(x, cb, Cf8, Xf8, cbsq);
  gemm_top2_kernel<<<M_PIX, 256, 0, stream>>>(Xf8, Cf8, cbsq, slots);
  reduce_rescore_gather<<<M_PIX / 4, 256, 0, stream>>>(x, cb, cbsq, slots, out);
}

// Round 5
// 144.004 us; speedup vs baseline: 1.4554x; 1.1728x over previous
//
#include <hip/hip_runtime.h>
#include <stdint.h>

#define M_PIX 8192
#define N_CB  16384
#define KD    256

typedef float f32x4 __attribute__((ext_vector_type(4)));
typedef int   i32x4 __attribute__((ext_vector_type(4)));
typedef int   i32x8 __attribute__((ext_vector_type(8)));
typedef unsigned long long ull;

// workspace layout (bytes)
#define OFF_CF8  (0ULL)            // codebook fp8 e4m3 (linear rows) : 4 MB
#define OFF_XF8  (4ULL << 20)      // x fp8 e4m3 (linear rows)        : 2 MB
#define OFF_CBSQ (6ULL << 20)      // ||c||^2 fp32                    : 64 KB
#define OFF_SLOT (7ULL << 20)      // float2 top2 [tile][pixel]       : 8 MB
#define WS_REQ   (15ULL << 20)

__device__ __forceinline__ unsigned int fkey(float s) {
  unsigned int f = __float_as_uint(s);
  return f ^ ((unsigned int)(((int)f) >> 31) | 0x80000000u);
}
// fp32 -> OCP e4m3fn, RNE, handles subnormals (step 2^-9), clamp 448
__device__ __forceinline__ unsigned char f2e4m3(float v) {
  float av = fminf(fabsf(v), 448.0f);
  const unsigned s = (__float_as_uint(v) >> 24) & 0x80u;
  unsigned m;
  if (av >= 0.015625f) {              // normal: round at mantissa bit 20
    unsigned u = __float_as_uint(av);
    u += 0x7FFFFu + ((u >> 20) & 1u);
    m = (((u >> 23) - 120u) << 3) | ((u >> 20) & 7u);
  } else {                            // subnormal
    m = (unsigned)(int)rintf(av * 512.0f);
  }
  return (unsigned char)(s | m);
}
__device__ __forceinline__ void gl_lds16(const unsigned char* g, char* l) {
  __builtin_amdgcn_global_load_lds(
      (const __attribute__((address_space(1))) unsigned int*)(const void*)g,
      (__attribute__((address_space(3))) unsigned int*)(void*)l,
      16, 0, 0);
}
// keep-smallest-2 on packed float keys: 3 VALU, no cndmask
__device__ __forceinline__ void ins2f(float k, float& v1, float& v2) {
  v2 = fminf(v2, fmaxf(v1, k));   // uses OLD v1
  v1 = fminf(v1, k);
}
// 32B fragment read from swizzled LDS: addr and addr^16
// (bit4 of the pre-swizzle base is 0, so the second 16B of the logical 32B
// chunk lives at addr^16 after the XOR swizzle).
__device__ __forceinline__ i32x8 ld32(const char* p, int addr) {
  const i32x4 lo = *(const i32x4*)(const void*)(p + addr);
  const i32x4 hi = *(const i32x4*)(const void*)(p + (addr ^ 16));
  return (i32x8){lo.x, lo.y, lo.z, lo.w, hi.x, hi.y, hi.z, hi.w};
}

// ---------------- kernel 1: fp32 -> fp8 e4m3 linear rows + cb norms ---------
__global__ __launch_bounds__(256) void prep_kernel(
    const float* __restrict__ x, const float* __restrict__ cb,
    unsigned char* __restrict__ Cf8, unsigned char* __restrict__ Xf8,
    float* __restrict__ cbsq) {
  const int wid = threadIdx.x >> 6, lane = threadIdx.x & 63;
  const int row = blockIdx.x * 4 + wid;        // grid = (N_CB+M_PIX)/4
  const bool isCb = (row < N_CB);
  const int rowL = isCb ? row : row - N_CB;
  const float* src = (isCb ? cb : x) + (size_t)rowL * KD;
  const float4 v = ((const float4*)src)[lane];
  uchar4 pk;
  pk.x = f2e4m3(v.x); pk.y = f2e4m3(v.y); pk.z = f2e4m3(v.z); pk.w = f2e4m3(v.w);
  *(uchar4*)(void*)((isCb ? Cf8 : Xf8) + (size_t)rowL * KD + lane * 4) = pk;
  if (isCb) {
    float ss = v.x*v.x + v.y*v.y + v.z*v.z + v.w*v.w;   // fp32 norm
    #pragma unroll
    for (int off = 32; off > 0; off >>= 1) ss += __shfl_xor(ss, off);
    if (lane == 0) cbsq[rowL] = ss;
  }
}

// ---------------- kernel 2: MX-fp8 GEMM (identity scales) + per-tile top-2 --
// s[p,n] = cbsq[n] - 2*(x8.c8). 8192 blocks / 4 waves (2x2, wave tile 64x64).
// GEMM core = R1's verified structure (61.6 us): K staged in two 128-col
// halves via global_load_lds into A,B 16 KB planes (row stride 128 B,
// XOR-swizzled through the pre-swizzled global source); frag read = 2x
// ds_read_b128; mfma_scale_f32_16x16x128_f8f6f4 with identity scales.
// NEW (this round): epilogue shrunk to ONE interleaved plane
// float2 P[128][32] (v1,v2 colocated) = 32768 B total LDS -> exactly
// 5 blocks/CU (was 36864 B -> 4); column XOR-swizzle (col ^ (row&31))
// spreads banks for both owner writes and scan reads; scan reads halve
// (128 B/thread vs 256). Owner phase: 8-op sorting network + BFI pack.

__global__ __launch_bounds__(256, 3) void gemm_top2_kernel(
    const unsigned char* __restrict__ Xf8, const unsigned char* __restrict__ Cf8,
    const float* __restrict__ cbsq, float2* __restrict__ slots) {
  __shared__ __align__(16) char smem[32768];
  char* A_s = smem;                       // 16 KB [128][128B]
  char* B_s = smem + 16384;               // 16 KB
  float2* P = (float2*)smem;              // overlay: [128][32] float2 = 32 KB

  const int tid = threadIdx.x;
  const int wid = tid >> 6, lane = tid & 63;
  const int wy = wid >> 1, wx = wid & 1;
  const int q = lane >> 4, c = lane & 15;

  // m-outer / n-inner per XCD: 16-block sweeps share one A-tile + B-strip
  const int bx = blockIdx.x & 7, bg = blockIdx.x >> 3;
  const int mt = bg >> 4;               // 0..63
  const int nt = bx * 16 + (bg & 15);   // 0..127
  const int m0 = mt * 128, n0 = nt * 128;

  // per-lane swizzled LDS frag byte addresses. All frag rows == c (mod 8),
  // so the swizzle term is one per-lane constant.
  const int swz = (c & 7) << 4;
  int aaddr[4], baddr[4];
  #pragma unroll
  for (int i = 0; i < 4; i++) {
    aaddr[i] = (((wy * 64 + i * 16 + c) * 128) + q * 32) ^ swz;
    baddr[i] = ((((wx * 64 + i * 16 + c) * 128) + q * 32) ^ swz) + 16384;
  }

  const f32x4 zf = {0.f, 0.f, 0.f, 0.f};
  f32x4 acc[4][4];
  #pragma unroll
  for (int i = 0; i < 4; i++)
    #pragma unroll
    for (int j = 0; j < 4; j++) acc[i][j] = zf;

  // staging: inverse-swizzled global source, linear LDS dest
  const int srow8 = lane >> 3;                       // row within 8-row chunk
  const int sgb = ((lane & 7) ^ srow8) * 16;         // pre-swizzled 16B slot

  #pragma unroll
  for (int hk = 0; hk < 2; hk++) {        // two 128-col K-halves
    if (hk) __syncthreads();              // prior half's frag reads done
    #pragma unroll
    for (int j = 0; j < 4; j++) {         // 16 chunks of 1 KB per operand
      const int chunk = j * 4 + wid;      // wave-uniform
      const int row = chunk * 8 + srow8;
      const int gb = sgb + hk * 128;
      gl_lds16(Xf8 + (size_t)(m0 + row) * KD + gb, A_s + chunk * 1024);
      gl_lds16(Cf8 + (size_t)(n0 + row) * KD + gb, B_s + chunk * 1024);
    }
    __syncthreads();
    i32x8 bfr[4];
    #pragma unroll
    for (int ni = 0; ni < 4; ni++)
      bfr[ni] = ld32(smem, baddr[ni]);
    #pragma unroll
    for (int mi = 0; mi < 4; mi++) {
      const i32x8 af = ld32(smem, aaddr[mi]);
      #pragma unroll
      for (int ni = 0; ni < 4; ni++)
        acc[mi][ni] = __builtin_amdgcn_mfma_scale_f32_16x16x128_f8f6f4(
            af, bfr[ni], acc[mi][ni], 0, 0,
            0, 0x7F7F7F7F,    // A scales: E8M0 127 = 1.0
            0, 0x7F7F7F7F);   // B scales: identity
    }
  }
  __syncthreads();   // tiles dead -> overlay plane P

  float cs[4]; unsigned colp[4];
  #pragma unroll
  for (int ni = 0; ni < 4; ni++) {
    colp[ni] = wx * 64 + ni * 16 + c;
    cs[ni] = cbsq[n0 + colp[ni]];
  }

  // owner phase: C/D layout col=lane&15, row=q*4+reg (m89/m91); col packed
  // into low 7 mantissa bits via BFI (|err|<=0.008, absorbed by k3
  // threshold). top-2-of-4 via 8-op sorting network. Store (v1,v2) as one
  // float2 at column (slot ^ (row&31)) — bijective per row, bank-spreading.
  #pragma unroll
  for (int mi = 0; mi < 4; mi++) {
    #pragma unroll
    for (int r = 0; r < 4; r++) {
      float k[4];
      #pragma unroll
      for (int ni = 0; ni < 4; ni++) {
        const float s = fmaf(-2.f, acc[mi][ni][r], cs[ni]);
        k[ni] = __uint_as_float((__float_as_uint(s) & 0xFFFFFF80u) |
                                (colp[ni] & 0x7Fu));
      }
      const float m1 = fminf(k[0], k[1]), M1 = fmaxf(k[0], k[1]);
      const float m2 = fminf(k[2], k[3]), M2 = fmaxf(k[2], k[3]);
      const float v1 = fminf(m1, m2);
      const float v2 = fminf(fmaxf(m1, m2), fminf(M1, M2));
      const int row = wy * 64 + mi * 16 + q * 4 + r;
      const int slot = wx * 16 + c;
      P[row * 32 + (slot ^ (row & 31))] = make_float2(v1, v2);
    }
  }
  __syncthreads();

  // scan: 2 threads/row over 16 float2 partial-pairs each, 1 shuffle merge
  {
    const float FINF = __uint_as_float(0x7F800000u);
    const int srow = tid >> 1, half = tid & 1;
    const int sw = srow & 31;
    float v1 = FINF, v2 = FINF;
    #pragma unroll
    for (int t = 0; t < 16; t++) {
      const float2 pv = P[srow * 32 + ((half * 16 + t) ^ sw)];
      ins2f(pv.x, v1, v2);
      ins2f(pv.y, v1, v2);
    }
    const float b1 = __shfl_xor(v1, 1), b2 = __shfl_xor(v2, 1);
    const float hi = fmaxf(v1, b1);
    v1 = fminf(v1, b1);
    v2 = fminf(fminf(v2, b2), hi);
    if (!half)
      slots[(size_t)nt * M_PIX + m0 + srow] = make_float2(v1, v2);
  }
}

// ---------------- kernel 3: global min + threshold exact rescore + gather ---
// Candidates with observed score < min+10 (noise + pack err + margin) are
// rescored exactly in fp32 (reads ORIGINAL fp32 cb rows); avg ~2 per pixel.
__global__ __launch_bounds__(256) void reduce_rescore_gather(
    const float* __restrict__ x, const float* __restrict__ cb,
    const float* __restrict__ cbsq, const float2* __restrict__ slots,
    float* __restrict__ out) {
  const int wid = threadIdx.x >> 6, lane = threadIdx.x & 63;
  const int pixel = blockIdx.x * 4 + wid;     // grid = 8192/4

  const float2 sA = slots[(size_t)lane * M_PIX + pixel];
  const float2 sB = slots[(size_t)(64 + lane) * M_PIX + pixel];
  const float sc[4] = {sA.x, sA.y, sB.x, sB.y};
  float mn = fminf(fminf(sc[0], sc[1]), fminf(sc[2], sc[3]));
  #pragma unroll
  for (int off = 1; off < 64; off <<= 1) mn = fminf(mn, __shfl_xor(mn, off));
  const float thr = mn + 10.0f;

  const float4 xv = ((const float4*)x)[(size_t)pixel * 64 + lane];
  ull best = ~0ULL;
  #pragma unroll
  for (int j = 0; j < 4; j++) {
    ull mask = __ballot(sc[j] < thr);
    while (mask) {
      const int src = (int)__ffsll((long long)mask) - 1;
      mask &= mask - 1;
      const float val = __shfl(sc[j], src);
      const unsigned ij = (unsigned)(((j >> 1) * 64 + src) * 128) +
                          (__float_as_uint(val) & 127u);
      const float4 cv = ((const float4*)cb)[(size_t)ij * 64 + lane];
      float d = xv.x*cv.x + xv.y*cv.y + xv.z*cv.z + xv.w*cv.w;
      #pragma unroll
      for (int off = 1; off < 64; off <<= 1) d += __shfl_xor(d, off);
      const float sv = fmaf(-2.f, d, cbsq[ij]);
      const ull k = ((ull)fkey(sv) << 32) | ij;   // tie -> lowest idx (np)
      best = k < best ? k : best;
    }
  }
  const unsigned w = (unsigned)best;
  ((float4*)out)[(size_t)pixel * 64 + lane] = ((const float4*)cb)[(size_t)w * 64 + lane];
}

// ---------------- fallback (ws too small): exact fp32 scan ------------------
__global__ __launch_bounds__(256) void fallback_kernel(
    const float* __restrict__ x, const float* __restrict__ cb,
    float* __restrict__ out) {
  __shared__ float xs[256];
  __shared__ unsigned long long keys[4];
  __shared__ int widx;
  const int p = blockIdx.x;
  const int tid = threadIdx.x, wid = tid >> 6, lane = tid & 63;
  xs[tid] = x[(size_t)p * KD + tid];
  __syncthreads();
  const float4 xv = ((const float4*)xs)[lane];
  float bestS = 3.4e38f; int bestI = 0;
  for (int k = wid; k < N_CB; k += 4) {
    const float4 cv = ((const float4*)cb)[(size_t)k * 64 + lane];
    float t = cv.x*(cv.x - 2.f*xv.x) + cv.y*(cv.y - 2.f*xv.y)
            + cv.z*(cv.z - 2.f*xv.z) + cv.w*(cv.w - 2.f*xv.w);
    #pragma unroll
    for (int off = 1; off < 64; off <<= 1) t += __shfl_xor(t, off);
    if (t < bestS) { bestS = t; bestI = k; }
  }
  if (lane == 0)
    keys[wid] = ((unsigned long long)fkey(bestS) << 32) | (unsigned int)bestI;
  __syncthreads();
  if (tid == 0) {
    unsigned long long m = keys[0];
    for (int i = 1; i < 4; i++) if (keys[i] < m) m = keys[i];
    widx = (int)(unsigned int)(m & 0xFFFFFFFFULL);
  }
  __syncthreads();
  out[(size_t)p * KD + tid] = cb[(size_t)widx * KD + tid];
}

extern "C" void kernel_launch(void* const* d_in, const int* in_sizes, int n_in,
                              void* d_out, int out_size, void* d_ws, size_t ws_size,
                              hipStream_t stream) {
  const float* x  = (const float*)d_in[0];   // [8192,256]
  const float* cb = (const float*)d_in[1];   // [16384,256]
  float* out = (float*)d_out;                // [8192,256]

  if (ws_size < WS_REQ) {
    fallback_kernel<<<M_PIX, 256, 0, stream>>>(x, cb, out);
    return;
  }

  char* ws = (char*)d_ws;
  unsigned char* Cf8 = (unsigned char*)(ws + OFF_CF8);
  unsigned char* Xf8 = (unsigned char*)(ws + OFF_XF8);
  float* cbsq        = (float*)(ws + OFF_CBSQ);
  float2* slots      = (float2*)(ws + OFF_SLOT);

  prep_kernel<<<(N_CB + M_PIX) / 4, 256, 0, stream>>>(x, cb, Cf8, Xf8, cbsq);
  gemm_top2_kernel<<<M_PIX, 256, 0, stream>>>(Xf8, Cf8, cbsq, slots);
  reduce_rescore_gather<<<M_PIX / 4, 256, 0, stream>>>(x, cb, cbsq, slots, out);
}